// Round 24
// baseline (101.379 us; speedup 1.0000x reference)
//
#include <hip/hip_runtime.h>
#include <math.h>

#define F_IN 256
#define OUT  64
#define LEAKY 0.2f
#define BSH  9                 // bucket shift: 512 nodes/bucket (pow2)
#define BSZ  512
#define CAP  12288             // csr4 capacity per bucket (mean 8163, sd 90)
#define EPB  4096              // edges per partition block
#define G1   586               // gemm blocks in kernel1 (rest overlap csr_build)

typedef __attribute__((ext_vector_type(4))) float f32x4;
typedef __attribute__((ext_vector_type(8))) __bf16 bf16x8;
typedef __attribute__((ext_vector_type(4))) unsigned int u32x4;

__device__ __forceinline__ unsigned cvt_pk_bf16(float lo, float hi) {
    unsigned r;
    asm volatile("v_cvt_pk_bf16_f32 %0, %1, %2" : "=v"(r) : "v"(lo), "v"(hi));
    return r;
}

__device__ __forceinline__ float bfl(unsigned u) {
    return __builtin_bit_cast(float, u << 16);
}
__device__ __forceinline__ float bfh(unsigned u) {
    return __builtin_bit_cast(float, u & 0xFFFF0000u);
}

// ================= shared gemm body (R23 verbatim) =================
__device__ __forceinline__ void gemm_body(
    int g, int t,
    const float* __restrict__ x, const float* __restrict__ W,
    const float* __restrict__ a1, const float* __restrict__ b1,
    const float* __restrict__ a2, const float* __restrict__ b2,
    unsigned short* __restrict__ h2, float* __restrict__ f1, float* __restrict__ f2,
    unsigned int* Wt, unsigned int* xsb, int N)
{
    const int wave = t >> 6;
    const int lane = t & 63;
    const int rowB = g * 128;

    for (int p = t; p < 64 * 32; p += 256) {
        int c = p & 63, gg = p >> 6;
        float f[8];
#pragma unroll
        for (int j = 0; j < 8; ++j) f[j] = W[(gg * 8 + j) * 64 + c];
        u32x4 d;
        d.x = cvt_pk_bf16(f[0], f[1]);
        d.y = cvt_pk_bf16(f[2], f[3]);
        d.z = cvt_pk_bf16(f[4], f[5]);
        d.w = cvt_pk_bf16(f[6], f[7]);
        int gs = gg ^ (c & 7);
        *(u32x4*)&Wt[c * 128 + gs * 4] = d;
    }

    const int lrow0 = lane >> 3;
    const int fcol  = (lane & 7) << 2;
    const int sslot = (lane & 7) >> 1;
    const int shalf = (lane & 1) << 1;
    size_t gsrc[4];
    unsigned woff[4];
#pragma unroll
    for (int i = 0; i < 4; ++i) {
        int row  = i * 8 + lrow0;
        int srow = rowB + wave * 32 + row; if (srow > N - 1) srow = N - 1;
        gsrc[i] = (size_t)srow * F_IN + fcol;
        woff[i] = row * 16 + ((sslot ^ (row & 3)) << 2) + shalf;
    }
    unsigned int* xw = &xsb[wave * 1024];

    f32x4 acc[2][4];
#pragma unroll
    for (int m = 0; m < 2; ++m)
#pragma unroll
        for (int n = 0; n < 4; ++n) acc[m][n] = (f32x4){0.f, 0.f, 0.f, 0.f};

    float4 la[4], lb[4];
#pragma unroll
    for (int i = 0; i < 4; ++i) la[i] = *(const float4*)&x[gsrc[i]];

    __syncthreads();

#pragma unroll
    for (int ks = 0; ks < 8; ++ks) {
        const int cur = ks & 1;
        if (ks < 7) {
            const int kc = (ks + 1) * 32;
            if (cur == 0) {
#pragma unroll
                for (int i = 0; i < 4; ++i) lb[i] = *(const float4*)&x[gsrc[i] + kc];
            } else {
#pragma unroll
                for (int i = 0; i < 4; ++i) la[i] = *(const float4*)&x[gsrc[i] + kc];
            }
            asm volatile("s_waitcnt vmcnt(4)" ::: "memory");
        } else {
            asm volatile("s_waitcnt vmcnt(0)" ::: "memory");
        }
        __builtin_amdgcn_sched_barrier(0);

#pragma unroll
        for (int i = 0; i < 4; ++i) {
            float4 v = (cur == 0) ? la[i] : lb[i];
            uint2 w;
            w.x = cvt_pk_bf16(v.x, v.y);
            w.y = cvt_pk_bf16(v.z, v.w);
            *(uint2*)&xw[cur * 512 + woff[i]] = w;
        }

        bf16x8 bfrag[4];
#pragma unroll
        for (int ns = 0; ns < 4; ++ns) {
            int c = ns * 16 + (lane & 15);
            int G = ks * 4 + (lane >> 4);
            u32x4 bw = *(u32x4*)&Wt[c * 128 + ((G ^ (c & 7)) << 2)];
            bfrag[ns] = __builtin_bit_cast(bf16x8, bw);
        }
#pragma unroll
        for (int ms = 0; ms < 2; ++ms) {
            int rr = ms * 16 + (lane & 15);
            int g0 = lane >> 4;
            u32x4 aw = *(u32x4*)&xw[cur * 512 + rr * 16 + ((g0 ^ (rr & 3)) << 2)];
            bf16x8 afrag = __builtin_bit_cast(bf16x8, aw);
#pragma unroll
            for (int ns = 0; ns < 4; ++ns)
                acc[ms][ns] = __builtin_amdgcn_mfma_f32_16x16x32_bf16(afrag, bfrag[ns],
                                                                      acc[ms][ns], 0, 0, 0);
        }
    }

    float A1v[4], A2v[4];
#pragma unroll
    for (int ns = 0; ns < 4; ++ns) {
        A1v[ns] = a1[ns * 16 + (lane & 15)];
        A2v[ns] = a2[ns * 16 + (lane & 15)];
    }
    float B1 = b1[0], B2 = b2[0];
#pragma unroll
    for (int ms = 0; ms < 2; ++ms) {
#pragma unroll
        for (int rr = 0; rr < 4; ++rr) {
            int grow = rowB + wave * 32 + ms * 16 + ((lane >> 4) << 2) + rr;
            float s1 = 0.f, s2 = 0.f;
#pragma unroll
            for (int ns = 0; ns < 4; ++ns) {
                float v = acc[ms][ns][rr];
                if (grow < N)
                    h2[(size_t)grow * OUT + ns * 16 + (lane & 15)] =
                        (unsigned short)(cvt_pk_bf16(v, v) & 0xffffu);
                s1 += v * A1v[ns];
                s2 += v * A2v[ns];
            }
#pragma unroll
            for (int off = 1; off < 16; off <<= 1) {
                s1 += __shfl_xor(s1, off);
                s2 += __shfl_xor(s2, off);
            }
            if ((lane & 15) == 0 && grow < N) { f1[grow] = s1 + B1; f2[grow] = s2 + B2; }
        }
    }
}

// ---------------- K1: edge partition (block-private) + first G1 gemm blocks ----------------
__global__ __launch_bounds__(256) void fused_part_gemm_kernel(
    const float* __restrict__ x, const float* __restrict__ W,
    const float* __restrict__ a1, const float* __restrict__ b1,
    const float* __restrict__ a2, const float* __restrict__ b2,
    unsigned short* __restrict__ h2, float* __restrict__ f1, float* __restrict__ f2,
    const int* __restrict__ esrc, const int* __restrict__ edst,
    int* __restrict__ runstart, int* __restrict__ cntmat, unsigned* __restrict__ ebkt,
    int N, int E, int nPart, int gemmBlocks)
{
    __shared__ __align__(16) unsigned int Wt[64 * 128];    // 32 KB
    __shared__ __align__(16) unsigned int xsb[4 * 1024];   // 16 KB

    const int bid = blockIdx.x;
    const int t   = threadIdx.x;
    const int r   = bid % 3;

    if (r == 2) {
        int c = bid / 3;
        if (c >= nPart) return;
        int* hist = (int*)Wt;
        int* off  = hist + 256;
        int* run  = hist + 512;
        int* sc0  = hist + 768;
        int* sc1  = hist + 1024;
        hist[t] = 0; off[t] = 0;
        __syncthreads();
        const int e0 = c * EPB;
        int ss[16], dd[16], bb[16];
#pragma unroll
        for (int k = 0; k < 4; ++k) {
            int i = e0 + k * 1024 + t * 4;
            if (i + 4 <= E) {
                int4 s4 = *(const int4*)&esrc[i];
                int4 d4 = *(const int4*)&edst[i];
                ss[k * 4 + 0] = s4.x; ss[k * 4 + 1] = s4.y;
                ss[k * 4 + 2] = s4.z; ss[k * 4 + 3] = s4.w;
                dd[k * 4 + 0] = d4.x; dd[k * 4 + 1] = d4.y;
                dd[k * 4 + 2] = d4.z; dd[k * 4 + 3] = d4.w;
#pragma unroll
                for (int q = 0; q < 4; ++q) {
                    bb[k * 4 + q] = ss[k * 4 + q] >> BSH;
                    atomicAdd(&hist[bb[k * 4 + q]], 1);
                }
            } else {
#pragma unroll
                for (int q = 0; q < 4; ++q) {
                    int e = i + q;
                    if (e < E) {
                        ss[k * 4 + q] = esrc[e];
                        dd[k * 4 + q] = edst[e];
                        bb[k * 4 + q] = ss[k * 4 + q] >> BSH;
                        atomicAdd(&hist[bb[k * 4 + q]], 1);
                    } else bb[k * 4 + q] = -1;
                }
            }
        }
        __syncthreads();
        sc0[t] = hist[t];
        __syncthreads();
        int* s = sc0; int* dsts = sc1;
        for (int d = 1; d < 256; d <<= 1) {
            dsts[t] = s[t] + (t >= d ? s[t - d] : 0);
            __syncthreads();
            int* tmp = s; s = dsts; dsts = tmp;
        }
        run[t] = s[t] - hist[t];
        runstart[c * 256 + t] = s[t] - hist[t];
        cntmat [c * 256 + t] = hist[t];
        __syncthreads();
#pragma unroll
        for (int k = 0; k < 16; ++k) {
            if (bb[k] >= 0) {
                int l = atomicAdd(&off[bb[k]], 1);
                ebkt[e0 + run[bb[k]] + l] = (unsigned)dd[k] |
                                            ((unsigned)(ss[k] & (BSZ - 1)) << 17);
            }
        }
        return;
    }

    const int g = (bid / 3) * 2 + r;
    if (g >= gemmBlocks) return;
    gemm_body(g, t, x, W, a1, b1, a2, b2, h2, f1, f2, Wt, xsb, N);
}

// ---------------- K2: csr_build (196 blocks) + remaining gemm blocks (1:1) ----------------
__global__ __launch_bounds__(256) void fused_csr_gemm_kernel(
    const float* __restrict__ x, const float* __restrict__ W,
    const float* __restrict__ a1, const float* __restrict__ b1,
    const float* __restrict__ a2, const float* __restrict__ b2,
    unsigned short* __restrict__ h2, float* __restrict__ f1, float* __restrict__ f2,
    const unsigned* __restrict__ ebkt, const int* __restrict__ runstart,
    const int* __restrict__ cntmat,
    int* __restrict__ counts, int* __restrict__ row_start, int* __restrict__ csr4,
    int N, int nPart, int nbk, int gemmLo, int gemmBlocks)
{
    __shared__ __align__(16) unsigned int Wt[64 * 128];    // 32 KB (csr aliases)
    __shared__ __align__(16) unsigned int xsb[4 * 1024];   // 16 KB

    const int bid = blockIdx.x;
    const int t   = threadIdx.x;

    if (bid & 1) {
        // ---------------- csr_build path (R21 body; aliases Wt) ----------------
        const int b = bid >> 1;
        if (b >= nbk) return;
        int* cnt = (int*)Wt;                  // 512
        int* cur = cnt + 512;                 // 512
        int* scA = cnt + 1024;                // 512
        int* scB = cnt + 1536;                // 512

        cnt[t] = 0; cnt[t + 256] = 0;
        __syncthreads();

        for (int c = t; c < nPart; c += 256) {
            int base = c * EPB + runstart[c * 256 + b];
            int n    = cntmat[c * 256 + b];
            for (int i = 0; i < n; ++i)
                atomicAdd(&cnt[ebkt[base + i] >> 17], 1);
        }
        __syncthreads();

        scA[t] = cnt[t]; scA[t + 256] = cnt[t + 256];
        __syncthreads();
        int* s = scA; int* dsts = scB;
        for (int d = 1; d < BSZ; d <<= 1) {
            int i0 = t, i1 = t + 256;
            dsts[i0] = s[i0] + (i0 >= d ? s[i0 - d] : 0);
            dsts[i1] = s[i1] + (i1 >= d ? s[i1 - d] : 0);
            __syncthreads();
            int* tmp = s; s = dsts; dsts = tmp;
        }

        const int nodeBase = b << BSH;
        const int e0out    = b * CAP;
#pragma unroll
        for (int j = 0; j < 2; ++j) {
            int i = t + j * 256;
            int excl = s[i] - cnt[i];
            cur[i] = excl;
            int gn = nodeBase + i;
            if (gn < N) {
                row_start[gn] = e0out + excl;
                counts[gn]    = cnt[i];
            }
        }
        __syncthreads();

        for (int c = t; c < nPart; c += 256) {
            int base = c * EPB + runstart[c * 256 + b];
            int n    = cntmat[c * 256 + b];
            for (int i = 0; i < n; ++i) {
                unsigned w = ebkt[base + i];
                int ls = w >> 17;
                int pos = e0out + atomicAdd(&cur[ls], 1);
                csr4[pos] = (int)(w & 0x1FFFFu);
            }
        }
        return;
    }

    const int g = gemmLo + (bid >> 1);
    if (g >= gemmBlocks) return;
    gemm_body(g, t, x, W, a1, b1, a2, b2, h2, f1, f2, Wt, xsb, N);
}

// ---------------- aggregation: 8-lane group per node, 8 nodes/wave (R22 verbatim) ----------------
__global__ __launch_bounds__(256) void aggregate_kernel(
    const unsigned short* __restrict__ h2, const float* __restrict__ f1,
    const float* __restrict__ f2,
    const int* __restrict__ row_start, const int* __restrict__ counts,
    const int* __restrict__ csr4, const float* __restrict__ out_bias,
    float* __restrict__ out, int N)
{
    const int t    = threadIdx.x;
    const int lane = t & 63;
    const int gl   = lane & 7;
    const int gb   = lane & 56;
    const int gw   = blockIdx.x * 32 + ((t >> 6) << 3) + (lane >> 3);
    if (gw >= N) return;

    const int base  = row_start[gw];
    const int deg   = counts[gw];
    const float f1n = f1[gw];

    float den = 0.f;
    float a[8] = {0.f, 0.f, 0.f, 0.f, 0.f, 0.f, 0.f, 0.f};

    for (int c0 = 0; c0 < deg; c0 += 8) {
        int  idx   = c0 + gl;
        bool valid = idx < deg;
        int   d = valid ? csr4[base + idx] : 0;
        float e = f1n + f2[d];
        e = (e > 0.f) ? e : LEAKY * e;
        float p = valid ? __expf(e) : 0.f;
        den += p;

        unsigned pack = ((unsigned)d << 15) | (cvt_pk_bf16(p, p) & 0x7FFFu);

        int lim = deg - c0; if (lim > 8) lim = 8;
        int j = 0;
        for (; j + 2 <= lim; j += 2) {
            unsigned pk0 = __shfl((int)pack, gb + j);
            unsigned pk1 = __shfl((int)pack, gb + j + 1);
            uint4 u0 = *(const uint4*)&h2[((pk0 >> 15) << 6) + (gl << 3)];
            uint4 u1 = *(const uint4*)&h2[((pk1 >> 15) << 6) + (gl << 3)];
            float p0 = __builtin_bit_cast(float, (pk0 & 0x7FFFu) << 16);
            float p1 = __builtin_bit_cast(float, (pk1 & 0x7FFFu) << 16);
            a[0] += p0 * bfl(u0.x) + p1 * bfl(u1.x);
            a[1] += p0 * bfh(u0.x) + p1 * bfh(u1.x);
            a[2] += p0 * bfl(u0.y) + p1 * bfl(u1.y);
            a[3] += p0 * bfh(u0.y) + p1 * bfh(u1.y);
            a[4] += p0 * bfl(u0.z) + p1 * bfl(u1.z);
            a[5] += p0 * bfh(u0.z) + p1 * bfh(u1.z);
            a[6] += p0 * bfl(u0.w) + p1 * bfl(u1.w);
            a[7] += p0 * bfh(u0.w) + p1 * bfh(u1.w);
        }
        if (j < lim) {
            unsigned pk = __shfl((int)pack, gb + j);
            uint4 u = *(const uint4*)&h2[((pk >> 15) << 6) + (gl << 3)];
            float pp = __builtin_bit_cast(float, (pk & 0x7FFFu) << 16);
            a[0] += pp * bfl(u.x);
            a[1] += pp * bfh(u.x);
            a[2] += pp * bfl(u.y);
            a[3] += pp * bfh(u.y);
            a[4] += pp * bfl(u.z);
            a[5] += pp * bfh(u.z);
            a[6] += pp * bfl(u.w);
            a[7] += pp * bfh(u.w);
        }
    }

    den += __shfl_xor(den, 1);
    den += __shfl_xor(den, 2);
    den += __shfl_xor(den, 4);

    float rd = (deg > 0) ? (1.f / den) : 0.f;
    float4 b0 = *(const float4*)&out_bias[(gl << 3) + 0];
    float4 b1v = *(const float4*)&out_bias[(gl << 3) + 4];
    float v[8];
    v[0] = a[0] * rd + b0.x;  v[1] = a[1] * rd + b0.y;
    v[2] = a[2] * rd + b0.z;  v[3] = a[3] * rd + b0.w;
    v[4] = a[4] * rd + b1v.x; v[5] = a[5] * rd + b1v.y;
    v[6] = a[6] * rd + b1v.z; v[7] = a[7] * rd + b1v.w;
#pragma unroll
    for (int k = 0; k < 8; ++k)
        v[k] = (v[k] > 0.f) ? v[k] : (__expf(v[k]) - 1.f);
    float4 r0 = {v[0], v[1], v[2], v[3]};
    float4 r1 = {v[4], v[5], v[6], v[7]};
    *(float4*)&out[((unsigned)gw << 6) + (gl << 3) + 0] = r0;
    *(float4*)&out[((unsigned)gw << 6) + (gl << 3) + 4] = r1;
}

extern "C" void kernel_launch(void* const* d_in, const int* in_sizes, int n_in,
                              void* d_out, int out_size, void* d_ws, size_t ws_size,
                              hipStream_t stream)
{
    const float* x        = (const float*)d_in[0];
    const float* W        = (const float*)d_in[1];
    const float* a1       = (const float*)d_in[2];
    const float* b1       = (const float*)d_in[3];
    const float* a2       = (const float*)d_in[4];
    const float* b2       = (const float*)d_in[5];
    const float* out_bias = (const float*)d_in[6];
    const int*   esrc     = (const int*)d_in[7];
    const int*   edst     = (const int*)d_in[8];
    const int N = in_sizes[0] / F_IN;
    const int E = in_sizes[7];
    float* out = (float*)d_out;

    char* wsp = (char*)d_ws;
    size_t off = 0;
    auto alloc = [&](size_t bytes) -> void* {
        void* p = wsp + off;
        off = (off + bytes + 255) & ~(size_t)255;
        return p;
    };
    const int nbk   = (N + BSZ - 1) >> BSH;               // 196 buckets
    const int nPart = (E + EPB - 1) / EPB;                // 391 partition blocks

    unsigned short* h2 = (unsigned short*)alloc((size_t)N * OUT * sizeof(unsigned short));
    float* f1          = (float*)alloc((size_t)N * sizeof(float));
    float* f2          = (float*)alloc((size_t)N * sizeof(float));
    int*   counts      = (int*)alloc((size_t)N * sizeof(int));
    int*   row_start   = (int*)alloc((size_t)N * sizeof(int));
    int*   runstart    = (int*)alloc((size_t)nPart * 256 * sizeof(int));
    int*   cntmat      = (int*)alloc((size_t)nPart * 256 * sizeof(int));
    unsigned* ebkt     = (unsigned*)alloc((size_t)nPart * EPB * sizeof(unsigned));
    int*   csr4        = (int*)alloc((size_t)nbk * CAP * sizeof(int));

    const int gemmBlocks = (N + 127) / 128;               // 782
    int nGroup1 = (G1 + 1) / 2;
    if (nPart > nGroup1) nGroup1 = nPart;                 // 391
    int nGroup2 = gemmBlocks - G1;                        // 196
    if (nbk > nGroup2) nGroup2 = nbk;

    fused_part_gemm_kernel<<<nGroup1 * 3, 256, 0, stream>>>(
        x, W, a1, b1, a2, b2, h2, f1, f2, esrc, edst, runstart, cntmat, ebkt,
        N, E, nPart, G1);
    fused_csr_gemm_kernel<<<nGroup2 * 2, 256, 0, stream>>>(
        x, W, a1, b1, a2, b2, h2, f1, f2, ebkt, runstart, cntmat,
        counts, row_start, csr4, N, nPart, nbk, G1, gemmBlocks);
    aggregate_kernel<<<(N + 31) / 32, 256, 0, stream>>>(h2, f1, f2, row_start, counts, csr4,
                                                        out_bias, out, N);
}